// Round 3
// baseline (479.081 us; speedup 1.0000x reference)
//
#include <hip/hip_runtime.h>
#include <hip/hip_fp16.h>

typedef _Float16 half8 __attribute__((ext_vector_type(8)));
typedef float floatx4 __attribute__((ext_vector_type(4)));

#define NPW 8   // nodes per wave in k_agg

// ---------------- QR: 3x3 Householder, LAPACK sgeqrf/sorgqr convention ----------------
__device__ inline void qr3_q(const double A[3][3], double Q[3][3]){
  double a[3][3];
#pragma unroll
  for (int r = 0; r < 3; r++)
#pragma unroll
    for (int c = 0; c < 3; c++) a[r][c] = A[r][c];

  double v1[3] = {1.0, 0.0, 0.0};
  double tau1 = 0.0;
  {
    double xn2 = a[1][0]*a[1][0] + a[2][0]*a[2][0];
    if (xn2 != 0.0){
      double alpha = a[0][0];
      double beta = -copysign(sqrt(alpha*alpha + xn2), alpha);
      tau1 = (beta - alpha) / beta;
      double inv = 1.0 / (alpha - beta);
      v1[1] = a[1][0] * inv;
      v1[2] = a[2][0] * inv;
#pragma unroll
      for (int c = 1; c < 3; c++){
        double w = a[0][c] + v1[1]*a[1][c] + v1[2]*a[2][c];
        double tw = tau1 * w;
        a[0][c] -= tw;
        a[1][c] -= tw * v1[1];
        a[2][c] -= tw * v1[2];
      }
    }
  }
  double tau2 = 0.0, v2 = 0.0;
  {
    double x2 = a[2][1];
    if (x2 != 0.0){
      double alpha = a[1][1];
      double beta = -copysign(sqrt(alpha*alpha + x2*x2), alpha);
      tau2 = (beta - alpha) / beta;
      v2 = x2 / (alpha - beta);
    }
  }
  double M[3][3] = {{1.0, 0.0, 0.0},
                    {0.0, 1.0 - tau2, -tau2*v2},
                    {0.0, -tau2*v2, 1.0 - tau2*v2*v2}};
#pragma unroll
  for (int c = 0; c < 3; c++){
    double w = v1[0]*M[0][c] + v1[1]*M[1][c] + v1[2]*M[2][c];
#pragma unroll
    for (int r = 0; r < 3; r++)
      Q[r][c] = M[r][c] - tau1 * v1[r] * w;
  }
}

// ---------------- CSR build ----------------
__global__ void k_count(const int* __restrict__ dst, int E, int* __restrict__ deg){
  int e = blockIdx.x*256 + threadIdx.x;
  if (e < E) atomicAdd(&deg[dst[e]], 1);
}

__global__ void k_scanA(const int* __restrict__ deg, int N, int* __restrict__ start, int* __restrict__ bsum){
  __shared__ int s[1024];
  int t = threadIdx.x;
  int i = blockIdx.x*1024 + t;
  int v = (i < N) ? deg[i] : 0;
  s[t] = v;
  __syncthreads();
  for (int off = 1; off < 1024; off <<= 1){
    int add = (t >= off) ? s[t - off] : 0;
    __syncthreads();
    s[t] += add;
    __syncthreads();
  }
  if (i < N) start[i] = s[t] - v;
  if (t == 1023) bsum[blockIdx.x] = s[t];
}

__global__ void k_scanB(int* __restrict__ bsum, int nb, int* __restrict__ start, int N){
  if (threadIdx.x == 0 && blockIdx.x == 0){
    int run = 0;
    for (int j = 0; j < nb; j++){ int tv = bsum[j]; bsum[j] = run; run += tv; }
    start[N] = run;
  }
}

__global__ void k_scanC(int* __restrict__ start, const int* __restrict__ bsum, int* __restrict__ cursor, int N){
  int i = blockIdx.x*256 + threadIdx.x;
  if (i < N){
    int v = start[i] + bsum[i >> 10];
    start[i] = v;
    cursor[i] = v;
  }
}

__global__ void k_fill(const int* __restrict__ src, const int* __restrict__ dst, int E,
                       int* __restrict__ cursor, int* __restrict__ csr){
  int e = blockIdx.x*256 + threadIdx.x;
  if (e < E){
    int p = atomicAdd(&cursor[dst[e]], 1);
    csr[p] = src[e];
  }
}

// wT16[l][n][k] = W_l[k][n]; l in 0..2 -> Wl, l==3 -> Wf
__global__ void k_prep_w(const float* __restrict__ Wl, const float* __restrict__ Wf,
                         _Float16* __restrict__ wT16){
  int idx = blockIdx.x*256 + threadIdx.x;
  int l = idx >> 14;
  int rem = idx & 16383;
  int n = rem >> 7;
  int k = rem & 127;
  const float* W = (l < 3) ? (Wl + (size_t)l*16384) : Wf;
  wT16[idx] = (_Float16)W[k*128 + n];
}

// ---------------- fp16 MFMA GEMM: H(Mx128) = X(Mx128) @ W(128x128) + bias ----------------
// 64 rows per block, 4 waves: wave handles 32 rows (2 rt) x 64 cols (4 ct).
__launch_bounds__(256)
__global__ void k_gemm_mfma(const void* __restrict__ Xin, const _Float16* __restrict__ Wt,
                            const float* __restrict__ bias, void* __restrict__ Hout,
                            int M, int in_fp32, int out_fp32){
  const int wave = threadIdx.x >> 6;
  const int lane = threadIdx.x & 63;
  const int quad = lane >> 4;
  const int l16  = lane & 15;
  const int rbase = blockIdx.x*64 + (wave & 1)*32;
  const int ctb = (wave >> 1)*4;

  const _Float16* X16 = (const _Float16*)Xin;
  const float*    X32 = (const float*)Xin;

  floatx4 acc[2][4] = {};
#pragma unroll
  for (int kc = 0; kc < 4; kc++){
    half8 af[2];
#pragma unroll
    for (int rt = 0; rt < 2; rt++){
      int r = rbase + rt*16 + l16;
      r = (r < M) ? r : (M - 1);
      if (in_fp32){
        const float* p = X32 + (size_t)r*128 + kc*32 + quad*8;
        float4 f0 = *(const float4*)p;
        float4 f1 = *(const float4*)(p + 4);
        half8 a;
        a[0]=(_Float16)f0.x; a[1]=(_Float16)f0.y; a[2]=(_Float16)f0.z; a[3]=(_Float16)f0.w;
        a[4]=(_Float16)f1.x; a[5]=(_Float16)f1.y; a[6]=(_Float16)f1.z; a[7]=(_Float16)f1.w;
        af[rt] = a;
      } else {
        af[rt] = *(const half8*)(X16 + (size_t)r*128 + kc*32 + quad*8);
      }
    }
#pragma unroll
    for (int ct = 0; ct < 4; ct++){
      half8 bf = *(const half8*)(Wt + (size_t)((ctb+ct)*16 + l16)*128 + kc*32 + quad*8);
      acc[0][ct] = __builtin_amdgcn_mfma_f32_16x16x32_f16(af[0], bf, acc[0][ct], 0, 0, 0);
      acc[1][ct] = __builtin_amdgcn_mfma_f32_16x16x32_f16(af[1], bf, acc[1][ct], 0, 0, 0);
    }
  }
#pragma unroll
  for (int rt = 0; rt < 2; rt++){
#pragma unroll
    for (int ct = 0; ct < 4; ct++){
      int col = (ctb+ct)*16 + l16;
      float bv = bias[col];
#pragma unroll
      for (int reg = 0; reg < 4; reg++){
        int r = rbase + rt*16 + quad*4 + reg;
        if (r < M){
          float v = acc[rt][ct][reg] + bv;
          if (out_fp32) ((float*)Hout)[(size_t)r*128 + col] = v;
          else          ((_Float16*)Hout)[(size_t)r*128 + col] = (_Float16)v;
        }
      }
    }
  }
}

// ---------------- aggregation (fp16 CSR gather) + 13 head dots -> dsws (SoA) ----------------
__launch_bounds__(256)
__global__ void k_agg(const _Float16* __restrict__ H, const int* __restrict__ csr,
                      const int* __restrict__ start, _Float16* __restrict__ Xout,
                      const float* __restrict__ Wc, const float* __restrict__ WR,
                      const float* __restrict__ Wt, float* __restrict__ dsws, int N){
  const int wave = threadIdx.x >> 6;
  const int lane = threadIdx.x & 63;
  const int node0 = (blockIdx.x*4 + wave)*NPW;
  if (node0 >= N) return;
  const int i0 = 2*lane, i1 = i0 + 1;

  // hoist head weights (reused for NPW nodes)
  float wc0 = Wc[i0], wc1 = Wc[i1];
  float wr0[9], wr1[9], wt0[3], wt1[3];
#pragma unroll
  for (int c = 0; c < 9; c++){ wr0[c] = WR[i0*9 + c]; wr1[c] = WR[i1*9 + c]; }
#pragma unroll
  for (int c = 0; c < 3; c++){ wt0[c] = Wt[i0*3 + c]; wt1[c] = Wt[i1*3 + c]; }

  const unsigned int* Hu = (const unsigned int*)H;

  for (int it = 0; it < NPW; it++){
    const int node = node0 + it;
    if (node >= N) return;
    const int s0 = start[node], s1 = start[node+1];
    float p0 = 0.f, p1 = 0.f, q0 = 0.f, q1 = 0.f;
    int e = s0;
    for (; e + 7 < s1; e += 8){
      unsigned int v0 = Hu[(size_t)csr[e]  *64 + lane];
      unsigned int v1 = Hu[(size_t)csr[e+1]*64 + lane];
      unsigned int v2 = Hu[(size_t)csr[e+2]*64 + lane];
      unsigned int v3 = Hu[(size_t)csr[e+3]*64 + lane];
      unsigned int v4 = Hu[(size_t)csr[e+4]*64 + lane];
      unsigned int v5 = Hu[(size_t)csr[e+5]*64 + lane];
      unsigned int v6 = Hu[(size_t)csr[e+6]*64 + lane];
      unsigned int v7 = Hu[(size_t)csr[e+7]*64 + lane];
      float2 f0 = __half22float2(*(__half2*)&v0);
      float2 f1 = __half22float2(*(__half2*)&v1);
      float2 f2 = __half22float2(*(__half2*)&v2);
      float2 f3 = __half22float2(*(__half2*)&v3);
      float2 f4 = __half22float2(*(__half2*)&v4);
      float2 f5 = __half22float2(*(__half2*)&v5);
      float2 f6 = __half22float2(*(__half2*)&v6);
      float2 f7 = __half22float2(*(__half2*)&v7);
      p0 += (f0.x + f1.x) + (f2.x + f3.x);
      p1 += (f0.y + f1.y) + (f2.y + f3.y);
      q0 += (f4.x + f5.x) + (f6.x + f7.x);
      q1 += (f4.y + f5.y) + (f6.y + f7.y);
    }
    for (; e < s1; e++){
      unsigned int v = Hu[(size_t)csr[e]*64 + lane];
      float2 f = __half22float2(*(__half2*)&v);
      p0 += f.x; p1 += f.y;
    }
    float acc0 = p0 + q0, acc1 = p1 + q1;

    __half2 ho = __floats2half2_rn(acc0, acc1);
    ((unsigned int*)Xout)[(size_t)node*64 + lane] = *(unsigned int*)&ho;

    float dsum[13];
    dsum[0] = acc0*wc0 + acc1*wc1;
#pragma unroll
    for (int c = 0; c < 9; c++) dsum[1+c]  = acc0*wr0[c] + acc1*wr1[c];
#pragma unroll
    for (int c = 0; c < 3; c++) dsum[10+c] = acc0*wt0[c] + acc1*wt1[c];
#pragma unroll
    for (int c = 0; c < 13; c++){
      float v = dsum[c];
#pragma unroll
      for (int off = 32; off > 0; off >>= 1) v += __shfl_xor(v, off);
      dsum[c] = v;
    }
    if (lane == 0){
#pragma unroll
      for (int c = 0; c < 13; c++) dsws[(size_t)c*N + node] = dsum[c];
    }
  }
}

// ---------------- node-parallel SE(3) epilogue: QR + pos/R/t updates ----------------
__launch_bounds__(256)
__global__ void k_se3(const float* __restrict__ dsws,
                      const float* __restrict__ bc, const float* __restrict__ bR,
                      const float* __restrict__ bt, const float* __restrict__ pos_in,
                      float* __restrict__ pos_o, float* __restrict__ R_o, float* __restrict__ t_o,
                      int layer, int N){
  const int n = blockIdx.x*256 + threadIdx.x;
  if (n >= N) return;
  float ds[13];
#pragma unroll
  for (int c = 0; c < 13; c++) ds[c] = dsws[(size_t)c*N + n];

  double A[3][3], Q[3][3];
#pragma unroll
  for (int r = 0; r < 3; r++)
#pragma unroll
    for (int c = 0; c < 3; c++)
      A[r][c] = (double)ds[1 + r*3 + c] + (double)bR[r*3 + c];
  qr3_q(A, Q);

  double pd = (double)ds[0] + (double)bc[0];
#pragma unroll
  for (int c = 0; c < 3; c++){
    double base = (layer == 0) ? (double)pos_in[n*3 + c] : (double)pos_o[n*3 + c];
    pos_o[n*3 + c] = (float)(base + pd);
  }

  if (layer == 0){
#pragma unroll
    for (int r = 0; r < 3; r++)
#pragma unroll
      for (int c = 0; c < 3; c++)
        R_o[n*9 + r*3 + c] = (float)Q[r][c];
  } else {
    double Rold[3][3];
#pragma unroll
    for (int r = 0; r < 3; r++)
#pragma unroll
      for (int c = 0; c < 3; c++)
        Rold[r][c] = (double)R_o[n*9 + r*3 + c];
#pragma unroll
    for (int r = 0; r < 3; r++)
#pragma unroll
      for (int c = 0; c < 3; c++){
        double s = Q[r][0]*Rold[0][c] + Q[r][1]*Rold[1][c] + Q[r][2]*Rold[2][c];
        R_o[n*9 + r*3 + c] = (float)s;
      }
  }
#pragma unroll
  for (int c = 0; c < 3; c++){
    double base = (layer == 0) ? 0.0 : (double)t_o[n*3 + c];
    t_o[n*3 + c] = (float)(base + (double)ds[10 + c] + (double)bt[c]);
  }
}

extern "C" void kernel_launch(void* const* d_in, const int* in_sizes, int n_in,
                              void* d_out, int out_size, void* d_ws, size_t ws_size,
                              hipStream_t stream){
  const float* x0  = (const float*)d_in[0];
  const float* pos = (const float*)d_in[1];
  const int*   ei  = (const int*)d_in[2];
  const float* Wl  = (const float*)d_in[3];
  const float* bl  = (const float*)d_in[4];
  const float* Wc  = (const float*)d_in[5];
  const float* bc  = (const float*)d_in[6];
  const float* WR  = (const float*)d_in[7];
  const float* bR  = (const float*)d_in[8];
  const float* Wt  = (const float*)d_in[9];
  const float* bt  = (const float*)d_in[10];
  const float* Wf  = (const float*)d_in[11];
  const float* bf  = (const float*)d_in[12];

  const int N = in_sizes[0] / 128;
  const int E = in_sizes[2] / 2;
  const int* srcp = ei;
  const int* dstp = ei + E;

  float* z_out = (float*)d_out;
  float* pos_o = z_out + (size_t)N*128;
  float* R_o   = pos_o + (size_t)N*3;
  float* t_o   = R_o   + (size_t)N*9;

  char* ws = (char*)d_ws;
  size_t off = 0;
  auto alloc = [&](size_t bytes)->char*{
    char* p = ws + off; off += (bytes + 511) & ~(size_t)511; return p;
  };
  _Float16* buf0h = (_Float16*)alloc((size_t)N*128*2);   // out16 ping
  _Float16* buf1h = (_Float16*)alloc((size_t)N*128*2);   // h16 buffer
  _Float16* wT16  = (_Float16*)alloc((size_t)4*128*128*2);
  float* dsws = (float*)alloc((size_t)13*N*4);
  int* startp = (int*)alloc((size_t)(N+1)*4);
  int* cursor = (int*)alloc((size_t)N*4);
  int* deg    = (int*)alloc((size_t)N*4);
  int* bsum   = (int*)alloc(4096);
  int* csr    = (int*)alloc((size_t)E*4);

  hipMemsetAsync(deg, 0, (size_t)N*4, stream);
  const int nb = (N + 1023) / 1024;
  k_count<<<dim3((E+255)/256), dim3(256), 0, stream>>>(dstp, E, deg);
  k_scanA<<<dim3(nb), dim3(1024), 0, stream>>>(deg, N, startp, bsum);
  k_scanB<<<dim3(1), dim3(64), 0, stream>>>(bsum, nb, startp, N);
  k_scanC<<<dim3((N+255)/256), dim3(256), 0, stream>>>(startp, bsum, cursor, N);
  k_fill <<<dim3((E+255)/256), dim3(256), 0, stream>>>(srcp, dstp, E, cursor, csr);
  k_prep_w<<<dim3(65536/256), dim3(256), 0, stream>>>(Wl, Wf, wT16);

  const int gemm_blocks = (N + 63)/64;
  const int agg_blocks  = (N + 4*NPW - 1)/(4*NPW);
  const int se3_blocks  = (N + 255)/256;

  const void* xcur = (const void*)x0;
  for (int layer = 0; layer < 3; layer++){
    k_gemm_mfma<<<dim3(gemm_blocks), dim3(256), 0, stream>>>(
        xcur, wT16 + (size_t)layer*16384, bl + (size_t)layer*128, (void*)buf1h,
        N, (layer == 0) ? 1 : 0, 0);
    k_agg<<<dim3(agg_blocks), dim3(256), 0, stream>>>(
        buf1h, csr, startp, buf0h,
        Wc + (size_t)layer*128, WR + (size_t)layer*128*9, Wt + (size_t)layer*128*3,
        dsws, N);
    k_se3<<<dim3(se3_blocks), dim3(256), 0, stream>>>(
        dsws, bc + layer, bR + (size_t)layer*9, bt + (size_t)layer*3,
        pos, pos_o, R_o, t_o, layer, N);
    xcur = (const void*)buf0h;
  }
  k_gemm_mfma<<<dim3(gemm_blocks), dim3(256), 0, stream>>>(
      xcur, wT16 + (size_t)3*16384, bf, (void*)z_out, N, 0, 1);
}